// Round 2
// baseline (335.684 us; speedup 1.0000x reference)
//
#include <hip/hip_runtime.h>
#include <hip/hip_bf16.h>

#define NQ      10
#define NSTATE  (1 << NQ)      // 1024
#define NLAYERS 4
#define D_IN    784
#define BLOCK   256

__global__ __launch_bounds__(BLOCK) void qnet_kernel(
    const float* __restrict__ x,
    const float* __restrict__ Wp,
    const float* __restrict__ bp,
    const float* __restrict__ qw,
    const float* __restrict__ Wo,
    const float* __restrict__ bo,
    float* __restrict__ out)
{
    __shared__ float2 st[NSTATE];              // statevector, 8 KB
    __shared__ float  gates[NLAYERS * NQ * 8]; // Rot 2x2 complex matrices
    __shared__ float  ryc[NQ], rys[NQ];        // RY embedding cos/sin
    __shared__ float  red[NQ * 4];             // cross-wave reduction scratch
    __shared__ float  zl[NQ];                  // Z expectations

    const int tid  = threadIdx.x;
    const int b    = blockIdx.x;
    const int lane = tid & 63;
    const int wv   = tid >> 6;

    // ---------- projection: h = tanh(x[b] @ Wp^T + bp) ----------
    float acc[NQ];
#pragma unroll
    for (int q = 0; q < NQ; q++) acc[q] = 0.f;
    const float* xrow = x + (size_t)b * D_IN;
    for (int d = tid; d < D_IN; d += BLOCK) {
        float xv = xrow[d];
#pragma unroll
        for (int q = 0; q < NQ; q++) acc[q] += xv * Wp[q * D_IN + d];
    }
#pragma unroll
    for (int q = 0; q < NQ; q++) {
#pragma unroll
        for (int off = 32; off > 0; off >>= 1) acc[q] += __shfl_down(acc[q], off, 64);
    }
    if (lane == 0) {
#pragma unroll
        for (int q = 0; q < NQ; q++) red[q * 4 + wv] = acc[q];
    }

    // ---------- Rot gate precompute (weights are batch-independent) ----------
    if (tid < NLAYERS * NQ) {
        float phi = qw[tid * 3 + 0];
        float th  = qw[tid * 3 + 1];
        float om  = qw[tid * 3 + 2];
        float s, c;   sincosf(0.5f * th, &s, &c);
        float ap = 0.5f * (phi + om), am = 0.5f * (phi - om);
        float sap, cap; sincosf(ap, &sap, &cap);
        float sam, cam; sincosf(am, &sam, &cam);
        float* g = &gates[tid * 8];
        // Rot = RZ(om) RY(th) RZ(phi):
        // U00 = e^{-i(phi+om)/2} c ; U01 = -e^{+i(phi-om)/2} s
        // U10 = e^{-i(phi-om)/2} s ; U11 = e^{+i(phi+om)/2} c
        g[0] =  cap * c;  g[1] = -sap * c;
        g[2] = -cam * s;  g[3] = -sam * s;
        g[4] =  cam * s;  g[5] = -sam * s;
        g[6] =  cap * c;  g[7] =  sap * c;
    }
    __syncthreads();

    if (tid < NQ) {
        float s = red[tid * 4 + 0] + red[tid * 4 + 1] + red[tid * 4 + 2] + red[tid * 4 + 3]
                + bp[tid];
        float h = tanhf(s);
        float sh, ch; sincosf(0.5f * h, &sh, &ch);
        ryc[tid] = ch; rys[tid] = sh;
    }

    // ---------- init statevector |0...0> ----------
    for (int i = tid; i < NSTATE; i += BLOCK) st[i] = make_float2(0.f, 0.f);
    if (tid == 0) st[0] = make_float2(1.f, 0.f);

    // ---------- RY angle embedding ----------
    for (int q = 0; q < NQ; q++) {
        __syncthreads();
        float c = ryc[q], s = rys[q];
        int m = 1 << (NQ - 1 - q);
#pragma unroll
        for (int rep = 0; rep < 2; rep++) {
            int p  = tid + rep * BLOCK;              // pair index 0..511
            int i0 = ((p & ~(m - 1)) << 1) | (p & (m - 1));
            int i1 = i0 | m;
            float2 a0 = st[i0], a1 = st[i1];
            st[i0] = make_float2(c * a0.x - s * a1.x, c * a0.y - s * a1.y);
            st[i1] = make_float2(s * a0.x + c * a1.x, s * a0.y + c * a1.y);
        }
    }

    // ---------- strongly-entangling layers ----------
    for (int l = 0; l < NLAYERS; l++) {
        for (int q = 0; q < NQ; q++) {
            __syncthreads();
            const float* g = &gates[(l * NQ + q) * 8];
            float g0 = g[0], g1 = g[1], g2 = g[2], g3 = g[3];
            float g4 = g[4], g5 = g[5], g6 = g[6], g7 = g[7];
            int m = 1 << (NQ - 1 - q);
#pragma unroll
            for (int rep = 0; rep < 2; rep++) {
                int p  = tid + rep * BLOCK;
                int i0 = ((p & ~(m - 1)) << 1) | (p & (m - 1));
                int i1 = i0 | m;
                float2 a0 = st[i0], a1 = st[i1];
                st[i0] = make_float2(g0 * a0.x - g1 * a0.y + g2 * a1.x - g3 * a1.y,
                                     g0 * a0.y + g1 * a0.x + g2 * a1.y + g3 * a1.x);
                st[i1] = make_float2(g4 * a0.x - g5 * a0.y + g6 * a1.x - g7 * a1.y,
                                     g4 * a0.y + g5 * a0.x + g6 * a1.y + g7 * a1.x);
            }
        }
        for (int q = 0; q < NQ; q++) {
            __syncthreads();
            int bc = NQ - 1 - q;
            int bt = NQ - 1 - ((q + 1) % NQ);
            int mc = 1 << bc, mt = 1 << bt;
            int ml = mc < mt ? mc : mt;
            int mh = mc < mt ? mt : mc;
            int i  = tid;                              // 256 swap pairs
            i = ((i & ~(ml - 1)) << 1) | (i & (ml - 1));
            i = ((i & ~(mh - 1)) << 1) | (i & (mh - 1));
            i |= mc;                                   // control=1, target=0
            float2 a0 = st[i], a1 = st[i | mt];
            st[i] = a1; st[i | mt] = a0;
        }
    }

    // ---------- measurement: Z expectation per qubit ----------
    __syncthreads();
    float zacc[NQ];
#pragma unroll
    for (int q = 0; q < NQ; q++) zacc[q] = 0.f;
    for (int i = tid; i < NSTATE; i += BLOCK) {
        float2 a = st[i];
        float p = a.x * a.x + a.y * a.y;
#pragma unroll
        for (int q = 0; q < NQ; q++) zacc[q] += ((i >> (NQ - 1 - q)) & 1) ? -p : p;
    }
#pragma unroll
    for (int q = 0; q < NQ; q++) {
#pragma unroll
        for (int off = 32; off > 0; off >>= 1) zacc[q] += __shfl_down(zacc[q], off, 64);
    }
    __syncthreads();   // reuse red[] — projection-phase reads are long done
    if (lane == 0) {
#pragma unroll
        for (int q = 0; q < NQ; q++) red[q * 4 + wv] = zacc[q];
    }
    __syncthreads();
    if (tid < NQ) {
        zl[tid] = red[tid * 4 + 0] + red[tid * 4 + 1] + red[tid * 4 + 2] + red[tid * 4 + 3];
    }
    __syncthreads();

    // ---------- output projection: out[b] = zl @ Wo^T + bo ----------
    if (tid < NQ) {
        float o = bo[tid];
#pragma unroll
        for (int q = 0; q < NQ; q++) o += zl[q] * Wo[tid * NQ + q];
        out[(size_t)b * NQ + tid] = o;
    }
}

extern "C" void kernel_launch(void* const* d_in, const int* in_sizes, int n_in,
                              void* d_out, int out_size, void* d_ws, size_t ws_size,
                              hipStream_t stream) {
    const float* x  = (const float*)d_in[0];
    const float* Wp = (const float*)d_in[1];
    const float* bp = (const float*)d_in[2];
    const float* qw = (const float*)d_in[3];
    const float* Wo = (const float*)d_in[4];
    const float* bo = (const float*)d_in[5];
    float* out = (float*)d_out;

    const int B = in_sizes[0] / D_IN;   // 8192
    hipLaunchKernelGGL(qnet_kernel, dim3(B), dim3(BLOCK), 0, stream,
                       x, Wp, bp, qw, Wo, bo, out);
}

// Round 3
// 261.728 us; speedup vs baseline: 1.2826x; 1.2826x over previous
//
#include <hip/hip_runtime.h>
#include <hip/hip_bf16.h>

#define NQ      10
#define NLAYERS 4
#define D_IN    784
#define BLOCK   256            // 4 waves = 4 batch states per block

// Index bit layout for amplitude i (10 bits): i = lane(6 bits, i[9:4]) * 16 + r(4 bits, i[3:0]).
// Qubit q lives at bit position P = 9-q.  P>=4 -> lane qubit (lane bit P-4), P<4 -> register qubit.

// ---- generic complex 2x2 gate (Rot) on bit position P ----
template<int P>
__device__ __forceinline__ void rot_gate(float2 amp[16], int lane, const float* __restrict__ g) {
    float4 gA = *(const float4*)(g);      // u00.re u00.im u01.re u01.im
    float4 gB = *(const float4*)(g + 4);  // u10.re u10.im u11.re u11.im
    if constexpr (P >= 4) {
        const int lb = 1 << (P - 4);
        const bool hi = (lane & lb) != 0;
        float gdx = hi ? gB.z : gA.x, gdy = hi ? gB.w : gA.y;  // diag coeff
        float gox = hi ? gB.x : gA.z, goy = hi ? gB.y : gA.w;  // off-diag coeff
#pragma unroll
        for (int r = 0; r < 16; r++) {
            float ox = __shfl_xor(amp[r].x, lb, 64);
            float oy = __shfl_xor(amp[r].y, lb, 64);
            float ax = amp[r].x, ay = amp[r].y;
            amp[r].x = gdx * ax - gdy * ay + gox * ox - goy * oy;
            amp[r].y = gdx * ay + gdy * ax + gox * oy + goy * ox;
        }
    } else {
        const int m = 1 << P;
#pragma unroll
        for (int r = 0; r < 16; r++) {
            if (!(r & m)) {
                const int r1 = r | m;
                float2 a0 = amp[r], a1 = amp[r1];
                amp[r].x  = gA.x * a0.x - gA.y * a0.y + gA.z * a1.x - gA.w * a1.y;
                amp[r].y  = gA.x * a0.y + gA.y * a0.x + gA.z * a1.y + gA.w * a1.x;
                amp[r1].x = gB.x * a0.x - gB.y * a0.y + gB.z * a1.x - gB.w * a1.y;
                amp[r1].y = gB.x * a0.y + gB.y * a0.x + gB.z * a1.y + gB.w * a1.x;
            }
        }
    }
}

// ---- real RY gate [[c,-s],[s,c]] on bit position P ----
template<int P>
__device__ __forceinline__ void ry_gate(float2 amp[16], int lane, float c, float s) {
    if constexpr (P >= 4) {
        const int lb = 1 << (P - 4);
        const bool hi = (lane & lb) != 0;
        const float ss = hi ? s : -s;     // new = c*own + ss*other
#pragma unroll
        for (int r = 0; r < 16; r++) {
            float ox = __shfl_xor(amp[r].x, lb, 64);
            float oy = __shfl_xor(amp[r].y, lb, 64);
            amp[r].x = c * amp[r].x + ss * ox;
            amp[r].y = c * amp[r].y + ss * oy;
        }
    } else {
        const int m = 1 << P;
#pragma unroll
        for (int r = 0; r < 16; r++) {
            if (!(r & m)) {
                const int r1 = r | m;
                float2 a0 = amp[r], a1 = amp[r1];
                amp[r].x  = c * a0.x - s * a1.x;
                amp[r].y  = c * a0.y - s * a1.y;
                amp[r1].x = s * a0.x + c * a1.x;
                amp[r1].y = s * a0.y + c * a1.y;
            }
        }
    }
}

// ---- CNOT: control bit PC, target bit PT ----
template<int PC, int PT>
__device__ __forceinline__ void cnot_gate(float2 amp[16], int lane) {
    if constexpr (PC >= 4 && PT >= 4) {               // lane-lane: conditional swap via shfl
        const int mc = 1 << (PC - 4), mt = 1 << (PT - 4);
        const bool ctl = (lane & mc) != 0;
#pragma unroll
        for (int r = 0; r < 16; r++) {
            float ox = __shfl_xor(amp[r].x, mt, 64);
            float oy = __shfl_xor(amp[r].y, mt, 64);
            amp[r].x = ctl ? ox : amp[r].x;
            amp[r].y = ctl ? oy : amp[r].y;
        }
    } else if constexpr (PC >= 4 && PT < 4) {         // lane control, register target
        const int mc = 1 << (PC - 4), mt = 1 << PT;
        const bool ctl = (lane & mc) != 0;
#pragma unroll
        for (int r = 0; r < 16; r++) {
            if (!(r & mt)) {
                const int r1 = r | mt;
                float2 a0 = amp[r], a1 = amp[r1];
                amp[r].x  = ctl ? a1.x : a0.x;  amp[r].y  = ctl ? a1.y : a0.y;
                amp[r1].x = ctl ? a0.x : a1.x;  amp[r1].y = ctl ? a0.y : a1.y;
            }
        }
    } else if constexpr (PC < 4 && PT >= 4) {         // register control, lane target
        const int mc = 1 << PC, mt = 1 << (PT - 4);
#pragma unroll
        for (int r = 0; r < 16; r++) {
            if (r & mc) {
                amp[r].x = __shfl_xor(amp[r].x, mt, 64);
                amp[r].y = __shfl_xor(amp[r].y, mt, 64);
            }
        }
    } else {                                          // register-register: free swap
        const int mc = 1 << PC, mt = 1 << PT;
#pragma unroll
        for (int r = 0; r < 16; r++) {
            if ((r & mc) && !(r & mt)) {
                const int r1 = r | mt;
                float2 t = amp[r]; amp[r] = amp[r1]; amp[r1] = t;
            }
        }
    }
}

__global__ __launch_bounds__(BLOCK, 4) void qnet_kernel(
    const float* __restrict__ x,
    const float* __restrict__ Wp,
    const float* __restrict__ bp,
    const float* __restrict__ qw,
    const float* __restrict__ Wo,
    const float* __restrict__ bo,
    float* __restrict__ out, int B)
{
    __shared__ float gates[NLAYERS * NQ * 8];  // 1.25 KB: Rot matrices (batch-independent)

    const int tid   = threadIdx.x;
    const int lane  = tid & 63;
    const int state = blockIdx.x * (BLOCK / 64) + (tid >> 6);

    // ---- Rot gate table (block-shared, one barrier in the whole kernel) ----
    if (tid < NLAYERS * NQ) {
        float phi = qw[tid * 3 + 0];
        float th  = qw[tid * 3 + 1];
        float om  = qw[tid * 3 + 2];
        float s, c;   sincosf(0.5f * th, &s, &c);
        float sap, cap; sincosf(0.5f * (phi + om), &sap, &cap);
        float sam, cam; sincosf(0.5f * (phi - om), &sam, &cam);
        float* g = &gates[tid * 8];
        g[0] =  cap * c;  g[1] = -sap * c;   // u00
        g[2] = -cam * s;  g[3] = -sam * s;   // u01
        g[4] =  cam * s;  g[5] = -sam * s;   // u10
        g[6] =  cap * c;  g[7] =  sap * c;   // u11
    }
    __syncthreads();
    if (state >= B) return;

    // ---- projection: h = tanh(x[state] @ Wp^T + bp), one wave per state ----
    float acc[NQ];
#pragma unroll
    for (int q = 0; q < NQ; q++) acc[q] = 0.f;
    const float* xrow = x + (size_t)state * D_IN;
    for (int d = lane; d < D_IN; d += 64) {
        float xv = xrow[d];
#pragma unroll
        for (int q = 0; q < NQ; q++) acc[q] += xv * Wp[q * D_IN + d];
    }
#pragma unroll
    for (int q = 0; q < NQ; q++) {
#pragma unroll
        for (int o = 1; o < 64; o <<= 1) acc[q] += __shfl_xor(acc[q], o, 64);
    }
    // lane q (q<10) owns qubit q's RY coefficients
    float myc = 1.f, mys = 0.f;
    if (lane < NQ) {
        float h = tanhf(acc[lane] + bp[lane]);
        sincosf(0.5f * h, &mys, &myc);
    }

    // ---- statevector |0..0> in registers ----
    float2 amp[16];
#pragma unroll
    for (int r = 0; r < 16; r++) amp[r] = make_float2(0.f, 0.f);
    if (lane == 0) amp[0].x = 1.f;

    // ---- RY embedding: qubit q at bit 9-q ----
    {
        float c, s;
#define RYQ(Q) c = __shfl(myc, Q, 64); s = __shfl(mys, Q, 64); ry_gate<9 - Q>(amp, lane, c, s);
        RYQ(0) RYQ(1) RYQ(2) RYQ(3) RYQ(4) RYQ(5) RYQ(6) RYQ(7) RYQ(8) RYQ(9)
#undef RYQ
    }

    // ---- strongly-entangling layers ----
    for (int l = 0; l < NLAYERS; l++) {
        const float* gl = &gates[l * NQ * 8];
        rot_gate<9>(amp, lane, gl + 0);
        rot_gate<8>(amp, lane, gl + 8);
        rot_gate<7>(amp, lane, gl + 16);
        rot_gate<6>(amp, lane, gl + 24);
        rot_gate<5>(amp, lane, gl + 32);
        rot_gate<4>(amp, lane, gl + 40);
        rot_gate<3>(amp, lane, gl + 48);
        rot_gate<2>(amp, lane, gl + 56);
        rot_gate<1>(amp, lane, gl + 64);
        rot_gate<0>(amp, lane, gl + 72);
        // CNOT ring q -> q+1 (mod 10); bits: control 9-q, target 9-(q+1)%10
        cnot_gate<9, 8>(amp, lane);
        cnot_gate<8, 7>(amp, lane);
        cnot_gate<7, 6>(amp, lane);
        cnot_gate<6, 5>(amp, lane);
        cnot_gate<5, 4>(amp, lane);
        cnot_gate<4, 3>(amp, lane);
        cnot_gate<3, 2>(amp, lane);
        cnot_gate<2, 1>(amp, lane);
        cnot_gate<1, 0>(amp, lane);
        cnot_gate<0, 9>(amp, lane);
    }

    // ---- measurement: Z expectation per qubit ----
    float S = 0.f, zr[4] = {0.f, 0.f, 0.f, 0.f};   // zr[b] = reg-bit-b signed sum
#pragma unroll
    for (int r = 0; r < 16; r++) {
        float pr = amp[r].x * amp[r].x + amp[r].y * amp[r].y;
        S += pr;
        zr[3] += (r & 8) ? -pr : pr;
        zr[2] += (r & 4) ? -pr : pr;
        zr[1] += (r & 2) ? -pr : pr;
        zr[0] += (r & 1) ? -pr : pr;
    }
    float zq[NQ];
    zq[6] = zr[3]; zq[7] = zr[2]; zq[8] = zr[1]; zq[9] = zr[0];   // reg qubits
#pragma unroll
    for (int q = 0; q < 6; q++)                                    // lane qubits: bit 5-q of lane
        zq[q] = ((lane >> (5 - q)) & 1) ? -S : S;
#pragma unroll
    for (int q = 0; q < NQ; q++) {
#pragma unroll
        for (int o = 1; o < 64; o <<= 1) zq[q] += __shfl_xor(zq[q], o, 64);
    }

    // ---- output projection: out[state] = zq @ Wo^T + bo ----
    if (lane < NQ) {
        float o = bo[lane];
#pragma unroll
        for (int q = 0; q < NQ; q++) o += zq[q] * Wo[lane * NQ + q];
        out[(size_t)state * NQ + lane] = o;
    }
}

extern "C" void kernel_launch(void* const* d_in, const int* in_sizes, int n_in,
                              void* d_out, int out_size, void* d_ws, size_t ws_size,
                              hipStream_t stream) {
    const float* x  = (const float*)d_in[0];
    const float* Wp = (const float*)d_in[1];
    const float* bp = (const float*)d_in[2];
    const float* qw = (const float*)d_in[3];
    const float* Wo = (const float*)d_in[4];
    const float* bo = (const float*)d_in[5];
    float* out = (float*)d_out;

    const int B = in_sizes[0] / D_IN;                    // 8192
    const int blocks = (B + (BLOCK / 64) - 1) / (BLOCK / 64);
    hipLaunchKernelGGL(qnet_kernel, dim3(blocks), dim3(BLOCK), 0, stream,
                       x, Wp, bp, qw, Wo, bo, out, B);
}

// Round 4
// 242.248 us; speedup vs baseline: 1.3857x; 1.0804x over previous
//
#include <hip/hip_runtime.h>
#include <hip/hip_bf16.h>

#define NQ      10
#define NLAYERS 4
#define D_IN    784
#define BLOCK   256            // 4 waves = 4 batch states per block

// Amplitude index i (10 bits): i = lane(6 bits, i[9:4]) * 16 + r(4 bits, i[3:0]).
// Qubit q sits at bit P = 9-q.  P>=4 -> lane qubit (lane bit P-4), P<4 -> register qubit.
// State is SoA in registers: ax[16], ay[16] (re/im), all indices compile-time constants.

// ---- generic complex 2x2 gate (Rot) on bit position P ----
template<int P>
__device__ __forceinline__ void rot_gate(float (&ax)[16], float (&ay)[16], int lane,
                                         float g0, float g1, float g2, float g3,
                                         float g4, float g5, float g6, float g7) {
    if constexpr (P >= 4) {
        const int lb = 1 << (P - 4);
        const bool hi = (lane & lb) != 0;
        const float gdx = hi ? g6 : g0, gdy = hi ? g7 : g1;   // diagonal coeff
        const float gox = hi ? g4 : g2, goy = hi ? g5 : g3;   // off-diagonal coeff
#pragma unroll
        for (int r = 0; r < 16; r++) {
            float ox = __shfl_xor(ax[r], lb, 64);
            float oy = __shfl_xor(ay[r], lb, 64);
            float vx = ax[r], vy = ay[r];
            ax[r] = gdx * vx - gdy * vy + gox * ox - goy * oy;
            ay[r] = gdx * vy + gdy * vx + gox * oy + goy * ox;
        }
    } else {
        const int m = 1 << P;
#pragma unroll
        for (int r = 0; r < 16; r++) {
            if (!(r & m)) {
                const int r1 = r | m;
                float x0 = ax[r], y0 = ay[r], x1 = ax[r1], y1 = ay[r1];
                ax[r]  = g0 * x0 - g1 * y0 + g2 * x1 - g3 * y1;
                ay[r]  = g0 * y0 + g1 * x0 + g2 * y1 + g3 * x1;
                ax[r1] = g4 * x0 - g5 * y0 + g6 * x1 - g7 * y1;
                ay[r1] = g4 * y0 + g5 * x0 + g6 * y1 + g7 * x1;
            }
        }
    }
}

// ---- real RY gate [[c,-s],[s,c]] on bit position P ----
template<int P>
__device__ __forceinline__ void ry_gate(float (&ax)[16], float (&ay)[16], int lane,
                                        float c, float s) {
    if constexpr (P >= 4) {
        const int lb = 1 << (P - 4);
        const float ss = ((lane & lb) != 0) ? s : -s;   // new = c*own + ss*other
#pragma unroll
        for (int r = 0; r < 16; r++) {
            float ox = __shfl_xor(ax[r], lb, 64);
            float oy = __shfl_xor(ay[r], lb, 64);
            ax[r] = c * ax[r] + ss * ox;
            ay[r] = c * ay[r] + ss * oy;
        }
    } else {
        const int m = 1 << P;
#pragma unroll
        for (int r = 0; r < 16; r++) {
            if (!(r & m)) {
                const int r1 = r | m;
                float x0 = ax[r], y0 = ay[r], x1 = ax[r1], y1 = ay[r1];
                ax[r]  = c * x0 - s * x1;
                ay[r]  = c * y0 - s * y1;
                ax[r1] = s * x0 + c * x1;
                ay[r1] = s * y0 + c * y1;
            }
        }
    }
}

// ---- CNOT: control bit PC, target bit PT ----
template<int PC, int PT>
__device__ __forceinline__ void cnot_gate(float (&ax)[16], float (&ay)[16], int lane) {
    if constexpr (PC >= 4 && PT >= 4) {               // lane-lane: conditional swap via shfl
        const int mc = 1 << (PC - 4), mt = 1 << (PT - 4);
        const bool ctl = (lane & mc) != 0;
#pragma unroll
        for (int r = 0; r < 16; r++) {
            float ox = __shfl_xor(ax[r], mt, 64);
            float oy = __shfl_xor(ay[r], mt, 64);
            ax[r] = ctl ? ox : ax[r];
            ay[r] = ctl ? oy : ay[r];
        }
    } else if constexpr (PC >= 4 && PT < 4) {         // lane control, register target
        const int mt = 1 << PT;
        const bool ctl = (lane & (1 << (PC - 4))) != 0;
#pragma unroll
        for (int r = 0; r < 16; r++) {
            if (!(r & mt)) {
                const int r1 = r | mt;
                float x0 = ax[r], y0 = ay[r], x1 = ax[r1], y1 = ay[r1];
                ax[r]  = ctl ? x1 : x0;  ay[r]  = ctl ? y1 : y0;
                ax[r1] = ctl ? x0 : x1;  ay[r1] = ctl ? y0 : y1;
            }
        }
    } else if constexpr (PC < 4 && PT >= 4) {         // register control, lane target
        const int mc = 1 << PC, mt = 1 << (PT - 4);
#pragma unroll
        for (int r = 0; r < 16; r++) {
            if (r & mc) {
                ax[r] = __shfl_xor(ax[r], mt, 64);
                ay[r] = __shfl_xor(ay[r], mt, 64);
            }
        }
    } else {                                          // register-register: free rename
        const int mc = 1 << PC, mt = 1 << PT;
#pragma unroll
        for (int r = 0; r < 16; r++) {
            if ((r & mc) && !(r & mt)) {
                const int r1 = r | mt;
                float t;
                t = ax[r]; ax[r] = ax[r1]; ax[r1] = t;
                t = ay[r]; ay[r] = ay[r1]; ay[r1] = t;
            }
        }
    }
}

__global__ __launch_bounds__(BLOCK)
__attribute__((amdgpu_waves_per_eu(2, 8)))
void qnet_kernel(
    const float* __restrict__ x,
    const float* __restrict__ Wp,
    const float* __restrict__ bp,
    const float* __restrict__ qw,
    const float* __restrict__ Wo,
    const float* __restrict__ bo,
    float* __restrict__ out, int B)
{
    __shared__ float gates[NLAYERS * NQ * 8];  // 1.25 KB: Rot matrices (batch-independent)

    const int tid   = threadIdx.x;
    const int lane  = tid & 63;
    const int state = blockIdx.x * (BLOCK / 64) + (tid >> 6);

    // ---- Rot gate table (block-shared; the only barrier in the kernel) ----
    if (tid < NLAYERS * NQ) {
        float phi = qw[tid * 3 + 0];
        float th  = qw[tid * 3 + 1];
        float om  = qw[tid * 3 + 2];
        float s, c;   sincosf(0.5f * th, &s, &c);
        float sap, cap; sincosf(0.5f * (phi + om), &sap, &cap);
        float sam, cam; sincosf(0.5f * (phi - om), &sam, &cam);
        float* g = &gates[tid * 8];
        g[0] =  cap * c;  g[1] = -sap * c;   // u00
        g[2] = -cam * s;  g[3] = -sam * s;   // u01
        g[4] =  cam * s;  g[5] = -sam * s;   // u10
        g[6] =  cap * c;  g[7] =  sap * c;   // u11
    }
    __syncthreads();
    if (state >= B) return;

    // ---- projection: h = tanh(x[state] @ Wp^T + bp), one wave per state ----
    float acc[NQ];
#pragma unroll
    for (int q = 0; q < NQ; q++) acc[q] = 0.f;
    const float* xrow = x + (size_t)state * D_IN;
    for (int d = lane; d < D_IN; d += 64) {
        float xv = xrow[d];
#pragma unroll
        for (int q = 0; q < NQ; q++) acc[q] += xv * Wp[q * D_IN + d];
    }
#pragma unroll
    for (int q = 0; q < NQ; q++) {
#pragma unroll
        for (int o = 1; o < 64; o <<= 1) acc[q] += __shfl_xor(acc[q], o, 64);
    }
    // lane q (q<10) owns qubit q's RY coefficients
    float myc = 1.f, mys = 0.f;
    if (lane < NQ) {
        float h = tanhf(acc[lane] + bp[lane]);
        sincosf(0.5f * h, &mys, &myc);
    }

    // ---- statevector |0..0> in registers (SoA) ----
    float ax[16], ay[16];
#pragma unroll
    for (int r = 0; r < 16; r++) { ax[r] = 0.f; ay[r] = 0.f; }
    if (lane == 0) ax[0] = 1.f;

    // ---- RY embedding: qubit q at bit 9-q ----
    {
        float c, s;
#define RYQ(Q) c = __shfl(myc, Q, 64); s = __shfl(mys, Q, 64); ry_gate<9 - Q>(ax, ay, lane, c, s);
        RYQ(0) RYQ(1) RYQ(2) RYQ(3) RYQ(4) RYQ(5) RYQ(6) RYQ(7) RYQ(8) RYQ(9)
#undef RYQ
    }

    // ---- strongly-entangling layers ----
    for (int l = 0; l < NLAYERS; l++) {
        const float* gl = &gates[l * NQ * 8];
#define ROTQ(Q) rot_gate<9 - Q>(ax, ay, lane, gl[Q*8+0], gl[Q*8+1], gl[Q*8+2], gl[Q*8+3], \
                                               gl[Q*8+4], gl[Q*8+5], gl[Q*8+6], gl[Q*8+7]);
        ROTQ(0) ROTQ(1) ROTQ(2) ROTQ(3) ROTQ(4) ROTQ(5) ROTQ(6) ROTQ(7) ROTQ(8) ROTQ(9)
#undef ROTQ
        // CNOT ring q -> q+1 (mod 10); bits: control 9-q, target 9-(q+1)%10
        cnot_gate<9, 8>(ax, ay, lane);
        cnot_gate<8, 7>(ax, ay, lane);
        cnot_gate<7, 6>(ax, ay, lane);
        cnot_gate<6, 5>(ax, ay, lane);
        cnot_gate<5, 4>(ax, ay, lane);
        cnot_gate<4, 3>(ax, ay, lane);
        cnot_gate<3, 2>(ax, ay, lane);
        cnot_gate<2, 1>(ax, ay, lane);
        cnot_gate<1, 0>(ax, ay, lane);
        cnot_gate<0, 9>(ax, ay, lane);
    }

    // ---- measurement: Z expectation per qubit ----
    float S = 0.f, zr3 = 0.f, zr2 = 0.f, zr1 = 0.f, zr0 = 0.f;
#pragma unroll
    for (int r = 0; r < 16; r++) {
        float pr = ax[r] * ax[r] + ay[r] * ay[r];
        S += pr;
        zr3 += (r & 8) ? -pr : pr;
        zr2 += (r & 4) ? -pr : pr;
        zr1 += (r & 2) ? -pr : pr;
        zr0 += (r & 1) ? -pr : pr;
    }
    float zq[NQ];
    zq[6] = zr3; zq[7] = zr2; zq[8] = zr1; zq[9] = zr0;       // register qubits
#pragma unroll
    for (int q = 0; q < 6; q++)                                // lane qubits: lane bit 5-q
        zq[q] = ((lane >> (5 - q)) & 1) ? -S : S;
#pragma unroll
    for (int q = 0; q < NQ; q++) {
#pragma unroll
        for (int o = 1; o < 64; o <<= 1) zq[q] += __shfl_xor(zq[q], o, 64);
    }

    // ---- output projection: out[state] = zq @ Wo^T + bo ----
    if (lane < NQ) {
        float o = bo[lane];
#pragma unroll
        for (int q = 0; q < NQ; q++) o += zq[q] * Wo[lane * NQ + q];
        out[(size_t)state * NQ + lane] = o;
    }
}

extern "C" void kernel_launch(void* const* d_in, const int* in_sizes, int n_in,
                              void* d_out, int out_size, void* d_ws, size_t ws_size,
                              hipStream_t stream) {
    const float* x  = (const float*)d_in[0];
    const float* Wp = (const float*)d_in[1];
    const float* bp = (const float*)d_in[2];
    const float* qw = (const float*)d_in[3];
    const float* Wo = (const float*)d_in[4];
    const float* bo = (const float*)d_in[5];
    float* out = (float*)d_out;

    const int B = in_sizes[0] / D_IN;                    // 8192
    const int blocks = (B + (BLOCK / 64) - 1) / (BLOCK / 64);
    hipLaunchKernelGGL(qnet_kernel, dim3(blocks), dim3(BLOCK), 0, stream,
                       x, Wp, bp, qw, Wo, bo, out, B);
}